// Round 2
// baseline (1172.045 us; speedup 1.0000x reference)
//
#include <hip/hip_runtime.h>

#define B_ 64
#define T_ 2048
#define I_ 128
#define H_ 128
#define CHUNK 128
#define NCHUNK (T_ / CHUNK)

// ---------------- Phase 1: xp = x @ W_xh^T + b_xh ----------------
__global__ __launch_bounds__(256) void xp_gemm(
    const float* __restrict__ x, const float* __restrict__ Wxh,
    const float* __restrict__ bxh, float* __restrict__ xp)
{
    __shared__ float ws[H_ * I_];   // 64 KB
    const int tid = threadIdx.x;
    {
        const float4* src = (const float4*)Wxh;
        float4* dst = (float4*)ws;
        #pragma unroll
        for (int i = 0; i < (H_ * I_ / 4) / 256; ++i)
            dst[tid + i * 256] = src[tid + i * 256];
    }
    __syncthreads();

    const int r  = tid & 127;
    const int ch = tid >> 7;
    const long row = (long)blockIdx.x * 128 + r;
    const float* xrow = x + row * I_;
    const float* wb = ws + ch * 64 * I_;

    float acc[64];
    #pragma unroll
    for (int c = 0; c < 64; ++c) acc[c] = 0.f;

    for (int k4 = 0; k4 < I_ / 4; ++k4) {
        const float4 xv = *(const float4*)(xrow + k4 * 4);
        #pragma unroll
        for (int c = 0; c < 64; ++c) {
            const float4 wv = *(const float4*)(wb + c * I_ + k4 * 4);
            acc[c] = fmaf(xv.x, wv.x, acc[c]);
            acc[c] = fmaf(xv.y, wv.y, acc[c]);
            acc[c] = fmaf(xv.z, wv.z, acc[c]);
            acc[c] = fmaf(xv.w, wv.w, acc[c]);
        }
    }

    float* orow = xp + row * H_ + ch * 64;
    const float4* bv = (const float4*)(bxh + ch * 64);
    #pragma unroll
    for (int c4 = 0; c4 < 16; ++c4) {
        const float4 b4 = bv[c4];
        float4 o;
        o.x = acc[c4 * 4 + 0] + b4.x;
        o.y = acc[c4 * 4 + 1] + b4.y;
        o.z = acc[c4 * 4 + 2] + b4.z;
        o.w = acc[c4 * 4 + 3] + b4.w;
        *(float4*)(orow + c4 * 4) = o;
    }
}

// Stage one 128-step xp chunk (64 KB) into LDS via async global_load_lds.
// 16 iters x 256 threads x 16 B. LDS base is wave-uniform; lane offset = ln*16 B.
__device__ __forceinline__ void stage_chunk(const float* __restrict__ g,
                                            float* l, int wv, int ln)
{
    #pragma unroll
    for (int i = 0; i < 16; ++i) {
        const int off = i * 1024 + wv * 256;          // floats, wave-uniform part
        __builtin_amdgcn_global_load_lds(
            (const __attribute__((address_space(1))) unsigned int*)(g + off + ln * 4),
            (__attribute__((address_space(3))) unsigned int*)(l + off),
            16, 0, 0);
    }
}

// ---------------- Phase 2: sequential scan, one block per batch ----------------
// 256 threads: lane pair (2j, 2j+1) owns output j; half = tid&1 selects K-half.
// hb padded: odd half starts at float 68 (+16B) so the pair's two broadcast
// b128 addresses hit DISJOINT bank groups -> conflict-free.
// xp staged through LDS in 128-step chunks (double buffered) so the per-step
// barrier needs only lgkmcnt(0) -- global stores never block the step loop.
__global__ __launch_bounds__(256, 1) void rnn_scan(
    const float* __restrict__ Whh, const float* __restrict__ bhh,
    float* __restrict__ seq /* xp in, h_seq out */, float* __restrict__ hlast)
{
    __shared__ float xpl[2][CHUNK * H_];   // 128 KB
    __shared__ float hb[2][136];           // slots 0..63, 68..131 (pad 4)

    const int tid  = threadIdx.x;
    const int j    = tid >> 1;
    const int half = tid & 1;
    const int b    = blockIdx.x;
    const int wv   = tid >> 6;
    const int ln   = tid & 63;

    float w[64];
    {
        const float* wr = Whh + j * H_ + half * 64;
        #pragma unroll
        for (int i4 = 0; i4 < 16; ++i4) {
            const float4 v = *(const float4*)(wr + i4 * 4);
            w[i4 * 4 + 0] = v.x; w[i4 * 4 + 1] = v.y;
            w[i4 * 4 + 2] = v.z; w[i4 * 4 + 3] = v.w;
        }
    }
    const float bj = bhh[j];
    if (tid < 136) { hb[0][tid] = 0.f; hb[1][tid] = 0.f; }

    float* xp = seq + (size_t)b * T_ * H_;

    stage_chunk(xp, &xpl[0][0], wv, ln);   // prologue: chunk 0

    const int slot = j + ((j >> 6) << 2);  // j<64 -> j ; j>=64 -> j+4
    int cur = 0;
    for (int c = 0; c < NCHUNK; ++c) {
        // boundary: my chunk-c loads done, then all waves rendezvous
        asm volatile("s_waitcnt vmcnt(0)" ::: "memory");
        __syncthreads();
        if (c + 1 < NCHUNK)
            stage_chunk(xp + (size_t)(c + 1) * CHUNK * H_, &xpl[(c + 1) & 1][0], wv, ln);

        const float* xb = &xpl[c & 1][0];
        float* sq = xp + (size_t)c * CHUNK * H_;

        for (int t = 0; t < CHUNK; ++t) {
            const float xcur = xb[t * H_ + j];            // pair-broadcast b32
            const float* hc = &hb[cur][half * 68];        // 272B: bank-disjoint halves
            float a0 = 0.f, a1 = 0.f, a2 = 0.f, a3 = 0.f;
            #pragma unroll
            for (int i4 = 0; i4 < 16; ++i4) {
                const float4 hv = *(const float4*)(hc + i4 * 4);
                a0 = fmaf(hv.x, w[i4 * 4 + 0], a0);
                a1 = fmaf(hv.y, w[i4 * 4 + 1], a1);
                a2 = fmaf(hv.z, w[i4 * 4 + 2], a2);
                a3 = fmaf(hv.w, w[i4 * 4 + 3], a3);
            }
            float s = (a0 + a1) + (a2 + a3);
            s += __shfl_xor(s, 1);                        // pair reduce
            const float pre = xcur + bj + s;
            const float e = exp2f(pre * 2.8853900817779268f);
            const float hnew = 1.f - 2.f * __builtin_amdgcn_rcpf(e + 1.f);
            if (!half) {
                hb[cur ^ 1][slot] = hnew;                 // next h buffer
                sq[t * H_ + j] = hnew;                    // h_seq (queued store, no wait)
            }
            asm volatile("s_waitcnt lgkmcnt(0)" ::: "memory");
            __builtin_amdgcn_s_barrier();                 // NO vmcnt drain per step
            cur ^= 1;
        }
    }
    if (!half) hlast[b * H_ + j] = hb[cur][slot];
}

extern "C" void kernel_launch(void* const* d_in, const int* in_sizes, int n_in,
                              void* d_out, int out_size, void* d_ws, size_t ws_size,
                              hipStream_t stream)
{
    const float* x   = (const float*)d_in[0];
    const float* Wxh = (const float*)d_in[1];
    const float* bxh = (const float*)d_in[2];
    const float* Whh = (const float*)d_in[3];
    const float* bhh = (const float*)d_in[4];
    float* out   = (float*)d_out;
    float* hlast = out + (size_t)B_ * T_ * H_;

    xp_gemm<<<(B_ * T_) / 128, 256, 0, stream>>>(x, Wxh, bxh, out);
    rnn_scan<<<B_, 256, 0, stream>>>(Whh, bhh, out, hlast);
}